// Round 5
// baseline (118.077 us; speedup 1.0000x reference)
//
#include <hip/hip_runtime.h>

typedef __attribute__((ext_vector_type(8))) short bf16x8;
typedef __attribute__((ext_vector_type(4))) float f32x4;
typedef __attribute__((ext_vector_type(4))) int   i32x4;

#define NROWS     131072
#define KCODES    1024
#define DDIM      64
#define OUT_ELEMS 8388608
#define NBLK      2048              // main blocks, 64 rows each
// d_ws layout
#define WS_PART   0                 // 2048 doubles (16 KB)
#define WS_SE     (16*1024)         // 1024 f32 exact ||e||^2
#define WS_SESC   (20*1024)         // 1024 f32, se * 2^21
#define WS_BPREP  (24*1024)         // 64 chunks * 4 KB lane-ready bf16 B-frags

// numpy pairwise sum pattern for n=64 (exact fp32, matches round-2 verified).
__device__ __forceinline__ float pairwise64_sq(const float* __restrict__ v) {
#pragma clang fp contract(off)
    float r[8];
#pragma unroll
    for (int j = 0; j < 8; ++j) r[j] = v[j] * v[j];
#pragma unroll
    for (int i = 8; i < 64; i += 8) {
#pragma unroll
        for (int j = 0; j < 8; ++j) r[j] += v[i + j] * v[i + j];
    }
    return ((r[0] + r[1]) + (r[2] + r[3])) + ((r[4] + r[5]) + (r[6] + r[7]));
}

__device__ __forceinline__ int med3i(int a, int b, int c) {
    // max(min(a,b), min(max(a,b),c)) — LLVM pattern-matches to v_med3_i32
    int mn = min(a, b), mx = max(a, b);
    return max(mn, min(mx, c));
}

__global__ __launch_bounds__(256) void prep_se(
    const float* __restrict__ emb, float* __restrict__ se, float* __restrict__ sesc)
{
#pragma clang fp contract(off)
    int k = blockIdx.x * 256 + threadIdx.x;
    if (k >= KCODES) return;
    float s = pairwise64_sq(emb + (k << 6));
    se[k]   = s;
    sesc[k] = s * 2097152.0f;   // * 2^21 (screen only)
}

// Lane-ready B fragments: chunk c (16 codes), frag f in {b0_klo,b0_khi,b1_klo,b1_khi}.
// Element j of lane l = split_{f>>1}( e[c*16+(l&15)][ (f&1)*32 + (l>>4)*8 + j ] ).
__global__ __launch_bounds__(64) void prep_b(
    const float* __restrict__ emb, unsigned short* __restrict__ bprep)
{
#pragma clang fp contract(off)
    const int c = blockIdx.x, l = threadIdx.x;
    const float* e = emb + ((c * 16 + (l & 15)) << 6);
#pragma unroll
    for (int f = 0; f < 4; ++f) {
        const int dbase = ((l >> 4) << 3) + (f & 1) * 32;
        const int s = f >> 1;
        unsigned short h[8];
#pragma unroll
        for (int j = 0; j < 8; ++j) {
            float v = e[dbase + j];
            unsigned u  = __float_as_uint(v);
            unsigned hi = u & 0xffff0000u;
            if (s == 1) {
                float r = v - __uint_as_float(hi);      // exact residual
                hi = __float_as_uint(r) & 0xffff0000u;  // truncate to bf16
            }
            h[j] = (unsigned short)(hi >> 16);
        }
        int4 w;
        w.x = h[0] | (h[1] << 16); w.y = h[2] | (h[3] << 16);
        w.z = h[4] | (h[5] << 16); w.w = h[6] | (h[7] << 16);
        *reinterpret_cast<int4*>(bprep + (((c * 4 + f) * 64 + l) << 3)) = w;
    }
}

__global__ __launch_bounds__(256) void vq_main(
    const float* __restrict__ lat, const float* __restrict__ emb,
    const float* __restrict__ se_g, const float* __restrict__ sesc_g,
    const unsigned short* __restrict__ bprep,
    float* __restrict__ out, double* __restrict__ partials)
{
#pragma clang fp contract(off)
    __shared__ float x_lds[64 * 68];     // 64 rows x 64 d, padded
    __shared__ int   keys_lds[64 * 49];  // 48 keys/row, padded stride
    __shared__ float eq_lds[64 * 68];    // gathered winning code rows
    __shared__ int   idx_lds[64];
    __shared__ double wsum[4];

    const int tid = threadIdx.x, l = tid & 63, w = tid >> 6;
    const int blk = blockIdx.x;
    const int n0 = blk * 64, b = n0 >> 12, hw0 = n0 & 4095;
    const float* latb = lat + ((size_t)b << 18) + hw0;

    // ---- stage x (coalesced: consecutive tid -> consecutive hw) ----
    {
        const int row = tid & 63, dbase = (tid >> 6) * 16;
#pragma unroll
        for (int dd = 0; dd < 16; ++dd) {
            int d = dbase + dd;
            x_lds[row * 68 + d] = latb[((size_t)d << 12) + row];
        }
    }
    __syncthreads();

    // ---- build A fragments (splits of -2x) in registers ----
    // A lane map (16x16x32): row = l&15, k = (l>>4)*8 + j.
    bf16x8 afrag[4];   // [split*2 + khalf]
    {
        const float* xr = x_lds + (w * 16 + (l & 15)) * 68;
        const int dk = (l >> 4) << 3;
#pragma unroll
        for (int h = 0; h < 2; ++h) {
            bf16x8 f0, f1;
#pragma unroll
            for (int j = 0; j < 8; ++j) {
                float m2x = xr[h * 32 + dk + j] * -2.0f;
                unsigned u  = __float_as_uint(m2x);
                unsigned hi = u & 0xffff0000u;
                float r = m2x - __uint_as_float(hi);
                unsigned hr = __float_as_uint(r) & 0xffff0000u;
                f0[j] = (short)(hi >> 16);
                f1[j] = (short)(hr >> 16);
            }
            afrag[0 + h] = f0;   // a0 (hi split)
            afrag[2 + h] = f1;   // a1 (lo split)
        }
    }

    // ---- sweep 64 chunks of 16 codes: 6 MFMA + keyed top-3 per lane ----
    int m1[4], m2[4], m3[4];
#pragma unroll
    for (int r = 0; r < 4; ++r) { m1[r] = m2[r] = m3[r] = 0x7fffffff; }

    const i32x4* bp = reinterpret_cast<const i32x4*>(bprep);
    i32x4 bbuf[2][4];
    float ses[2];
#pragma unroll
    for (int f = 0; f < 4; ++f) bbuf[0][f] = bp[f * 64 + l];
    ses[0] = sesc_g[l & 15];

#pragma unroll 2
    for (int c = 0; c < 64; ++c) {
        const int cur = c & 1, nxt = cur ^ 1;
        if (c < 63) {
#pragma unroll
            for (int f = 0; f < 4; ++f) bbuf[nxt][f] = bp[(c + 1) * 256 + f * 64 + l];
            ses[nxt] = sesc_g[(c + 1) * 16 + (l & 15)];
        }
        bf16x8 b0 = __builtin_bit_cast(bf16x8, bbuf[cur][0]);
        bf16x8 b1 = __builtin_bit_cast(bf16x8, bbuf[cur][1]);
        bf16x8 b2 = __builtin_bit_cast(bf16x8, bbuf[cur][2]);
        bf16x8 b3 = __builtin_bit_cast(bf16x8, bbuf[cur][3]);
        f32x4 accA = {0.f, 0.f, 0.f, 0.f}, accB = {0.f, 0.f, 0.f, 0.f};
        accA = __builtin_amdgcn_mfma_f32_16x16x32_bf16(afrag[0], b0, accA, 0, 0, 0); // a0.b0 klo
        accB = __builtin_amdgcn_mfma_f32_16x16x32_bf16(afrag[1], b1, accB, 0, 0, 0); // a0.b0 khi
        accA = __builtin_amdgcn_mfma_f32_16x16x32_bf16(afrag[0], b2, accA, 0, 0, 0); // a0.b1 klo
        accB = __builtin_amdgcn_mfma_f32_16x16x32_bf16(afrag[1], b3, accB, 0, 0, 0); // a0.b1 khi
        accA = __builtin_amdgcn_mfma_f32_16x16x32_bf16(afrag[2], b0, accA, 0, 0, 0); // a1.b0 klo
        accB = __builtin_amdgcn_mfma_f32_16x16x32_bf16(afrag[3], b1, accB, 0, 0, 0); // a1.b0 khi
        const float sev = ses[cur];
        const int code0 = (c << 4) + (l & 15);
#pragma unroll
        for (int r = 0; r < 4; ++r) {
            float tv = accA[r] + accB[r];
            float uf = fmaf(tv, 2097152.0f, sev);        // (t~)*2^21 (se pre-scaled)
            int u = (((int)uf) << 10) | code0;           // monotone key, code in low 10
            int n1 = min(u, m1[r]);
            int n2 = med3i(u, m1[r], m2[r]);
            int n3 = med3i(max(u, m1[r]), m2[r], m3[r]);
            m1[r] = n1; m2[r] = n2; m3[r] = n3;
        }
    }

    // ---- dump per-lane top-3 keys (C map: row = (l>>4)*4+reg, col = l&15) ----
    {
        const int c0 = l & 15;
#pragma unroll
        for (int r = 0; r < 4; ++r) {
            const int rloc = w * 16 + ((l >> 4) << 2) + r;
            keys_lds[rloc * 49 + c0 * 3 + 0] = m1[r];
            keys_lds[rloc * 49 + c0 * 3 + 1] = m2[r];
            keys_lds[rloc * 49 + c0 * 3 + 2] = m3[r];
        }
    }
    __syncthreads();

    // ---- finalize: exact fp32 re-check of in-margin candidates ----
    if (tid < 64) {
        const int row = tid;
        int mk = 0x7fffffff;
        for (int i = 0; i < 48; ++i) mk = min(mk, keys_lds[row * 49 + i]);
        const int lim = mk + ((169 << 10) + 1023);   // margin 169/2^21 ~ 8e-5 in t units
        const float sx = pairwise64_sq(&x_lds[row * 68]);
        float bestd = 3.4e38f; int besti = KCODES;
        for (int i = 0; i < 48; ++i) {
            int key = keys_lds[row * 49 + i];
            if (key <= lim) {
                int code = key & 1023;
                const float* e = emb + (code << 6);
                float g = 0.0f;
#pragma unroll
                for (int d = 0; d < 64; ++d) g = fmaf(x_lds[row * 68 + d], e[d], g);
                float s_   = sx + se_g[code];    // fl32
                float dist = s_ - 2.0f * g;      // 2g exact; fl32 subtract
                if (dist < bestd || (dist == bestd && code < besti)) { bestd = dist; besti = code; }
            }
        }
        idx_lds[row] = besti;
    }
    __syncthreads();

    // ---- gather winning code rows to LDS ----
    {
        const int r = tid >> 2, seg = tid & 3;
        const float4* src = reinterpret_cast<const float4*>(emb + (idx_lds[r] << 6) + seg * 16);
#pragma unroll
        for (int q = 0; q < 4; ++q) {
            float4 v = src[q];
            int base = r * 68 + seg * 16 + q * 4;
            eq_lds[base + 0] = v.x; eq_lds[base + 1] = v.y;
            eq_lds[base + 2] = v.z; eq_lds[base + 3] = v.w;
        }
    }
    __syncthreads();

    // ---- outputs: q_st (coalesced), inds, loss partial ----
    double lsum = 0.0;
    {
        const float aq = 1.0f / 8388608.0f;   // 2^-23 exactly
        const int row = tid & 63, dbase = (tid >> 6) * 16;
        float* ob = out + ((size_t)b << 18) + hw0 + row;
#pragma unroll
        for (int dd = 0; dd < 16; ++dd) {
            int d = dbase + dd;
            float xv = x_lds[row * 68 + d];
            float qd = eq_lds[row * 68 + d];
            float v  = (xv + aq * qd) + ((1.0f - aq) * qd - xv);
            ob[(size_t)d << 12] = v;
            float diff = qd - xv;
            lsum += (double)diff * (double)diff;
        }
    }
    if (tid < 64) out[OUT_ELEMS + 1 + (size_t)blk * 64 + tid] = (float)idx_lds[tid];

#pragma unroll
    for (int off = 32; off > 0; off >>= 1) lsum += __shfl_down(lsum, off, 64);
    if (l == 0) wsum[w] = lsum;
    __syncthreads();
    if (tid == 0) partials[blk] = (wsum[0] + wsum[1]) + (wsum[2] + wsum[3]);
}

__global__ __launch_bounds__(512) void vq_finish(
    const double* __restrict__ partials, float* __restrict__ out)
{
    __shared__ double lds[8];
    const int t = threadIdx.x;
    double s = partials[t] + partials[t + 512] + partials[t + 1024] + partials[t + 1536];
#pragma unroll
    for (int off = 32; off > 0; off >>= 1) s += __shfl_down(s, off, 64);
    if ((t & 63) == 0) lds[t >> 6] = s;
    __syncthreads();
    if (t == 0) {
        double tot = 0.0;
#pragma unroll
        for (int i = 0; i < 8; ++i) tot += lds[i];
        out[OUT_ELEMS] = (float)(0.75 * tot / (double)OUT_ELEMS);
    }
}

extern "C" void kernel_launch(void* const* d_in, const int* in_sizes, int n_in,
                              void* d_out, int out_size, void* d_ws, size_t ws_size,
                              hipStream_t stream)
{
    const float* lat = (const float*)d_in[0];
    const float* emb = (const float*)d_in[1];
    float* out = (float*)d_out;
    char* ws = (char*)d_ws;

    double* partials        = (double*)(ws + WS_PART);
    float* se               = (float*)(ws + WS_SE);
    float* sesc             = (float*)(ws + WS_SESC);
    unsigned short* bprep   = (unsigned short*)(ws + WS_BPREP);

    prep_se<<<dim3(4),   dim3(256), 0, stream>>>(emb, se, sesc);
    prep_b <<<dim3(64),  dim3(64),  0, stream>>>(emb, bprep);
    vq_main<<<dim3(NBLK), dim3(256), 0, stream>>>(lat, emb, se, sesc, bprep, out, partials);
    vq_finish<<<dim3(1), dim3(512), 0, stream>>>(partials, out);
}

// Round 6
// 117.484 us; speedup vs baseline: 1.0050x; 1.0050x over previous
//
#include <hip/hip_runtime.h>

typedef __attribute__((ext_vector_type(8))) short bf16x8;
typedef __attribute__((ext_vector_type(4))) float f32x4;
typedef __attribute__((ext_vector_type(4))) int   i32x4;

#define NROWS     131072
#define KCODES    1024
#define DDIM      64
#define OUT_ELEMS 8388608
#define NBLK      2048              // main blocks, 64 rows each
// d_ws layout
#define WS_PART   0                 // 2048 doubles (16 KB)
#define WS_SE     (16*1024)         // 1024 f32 exact ||e||^2
#define WS_SESC   (20*1024)         // 1024 f32, se * 2^21
#define WS_BPREP  (24*1024)         // 64 chunks * 4 KB lane-ready bf16 B-frags

// numpy pairwise sum pattern for n=64 (exact fp32, matches round-2 verified).
__device__ __forceinline__ float pairwise64_sq(const float* __restrict__ v) {
#pragma clang fp contract(off)
    float r[8];
#pragma unroll
    for (int j = 0; j < 8; ++j) r[j] = v[j] * v[j];
#pragma unroll
    for (int i = 8; i < 64; i += 8) {
#pragma unroll
        for (int j = 0; j < 8; ++j) r[j] += v[i + j] * v[i + j];
    }
    return ((r[0] + r[1]) + (r[2] + r[3])) + ((r[4] + r[5]) + (r[6] + r[7]));
}

__device__ __forceinline__ int med3i(int a, int b, int c) {
    // max(min(a,b), min(max(a,b),c)) — LLVM pattern-matches to v_med3_i32
    int mn = min(a, b), mx = max(a, b);
    return max(mn, min(mx, c));
}

__global__ __launch_bounds__(256) void prep_se(
    const float* __restrict__ emb, float* __restrict__ se, float* __restrict__ sesc)
{
#pragma clang fp contract(off)
    int k = blockIdx.x * 256 + threadIdx.x;
    if (k >= KCODES) return;
    float s = pairwise64_sq(emb + (k << 6));
    se[k]   = s;
    sesc[k] = s * 2097152.0f;   // * 2^21 (screen only)
}

// Lane-ready B fragments: chunk c (16 codes), frag f in {b0_klo,b0_khi,b1_klo,b1_khi}.
// Element j of lane l = split_{f>>1}( e[c*16+(l&15)][ (f&1)*32 + (l>>4)*8 + j ] ).
__global__ __launch_bounds__(64) void prep_b(
    const float* __restrict__ emb, unsigned short* __restrict__ bprep)
{
#pragma clang fp contract(off)
    const int c = blockIdx.x, l = threadIdx.x;
    const float* e = emb + ((c * 16 + (l & 15)) << 6);
#pragma unroll
    for (int f = 0; f < 4; ++f) {
        const int dbase = ((l >> 4) << 3) + (f & 1) * 32;
        const int s = f >> 1;
        unsigned short h[8];
#pragma unroll
        for (int j = 0; j < 8; ++j) {
            float v = e[dbase + j];
            unsigned u  = __float_as_uint(v);
            unsigned hi = u & 0xffff0000u;
            if (s == 1) {
                float r = v - __uint_as_float(hi);      // exact residual
                hi = __float_as_uint(r) & 0xffff0000u;  // truncate to bf16
            }
            h[j] = (unsigned short)(hi >> 16);
        }
        int4 w;
        w.x = h[0] | (h[1] << 16); w.y = h[2] | (h[3] << 16);
        w.z = h[4] | (h[5] << 16); w.w = h[6] | (h[7] << 16);
        *reinterpret_cast<int4*>(bprep + (((c * 4 + f) * 64 + l) << 3)) = w;
    }
}

__global__ __launch_bounds__(256) void vq_main(
    const float* __restrict__ lat, const float* __restrict__ emb,
    const float* __restrict__ se_g, const float* __restrict__ sesc_g,
    const unsigned short* __restrict__ bprep,
    float* __restrict__ out, double* __restrict__ partials)
{
#pragma clang fp contract(off)
    __shared__ float x_lds[64 * 68];     // 64 rows x 64 d, padded
    __shared__ int   keys_lds[64 * 49];  // 48 keys/row, padded stride
    __shared__ float eq_lds[64 * 68];    // gathered winning code rows
    __shared__ int   idx_lds[64];
    __shared__ double wsum[4];

    const int tid = threadIdx.x, l = tid & 63, w = tid >> 6;
    const int blk = blockIdx.x;
    const int n0 = blk * 64, b = n0 >> 12, hw0 = n0 & 4095;
    const float* latb = lat + ((size_t)b << 18) + hw0;

    // ---- stage x (coalesced: consecutive tid -> consecutive hw) ----
    {
        const int row = tid & 63, dbase = (tid >> 6) * 16;
#pragma unroll
        for (int dd = 0; dd < 16; ++dd) {
            int d = dbase + dd;
            x_lds[row * 68 + d] = latb[((size_t)d << 12) + row];
        }
    }
    __syncthreads();

    // ---- build A fragments (splits of -2x) in registers ----
    // A lane map (16x16x32): row = l&15, k = (l>>4)*8 + j.
    bf16x8 afrag[4];   // [split*2 + khalf]
    {
        const float* xr = x_lds + (w * 16 + (l & 15)) * 68;
        const int dk = (l >> 4) << 3;
#pragma unroll
        for (int h = 0; h < 2; ++h) {
            bf16x8 f0, f1;
#pragma unroll
            for (int j = 0; j < 8; ++j) {
                float m2x = xr[h * 32 + dk + j] * -2.0f;
                unsigned u  = __float_as_uint(m2x);
                unsigned hi = u & 0xffff0000u;
                float r = m2x - __uint_as_float(hi);
                unsigned hr = __float_as_uint(r) & 0xffff0000u;
                f0[j] = (short)(hi >> 16);
                f1[j] = (short)(hr >> 16);
            }
            afrag[0 + h] = f0;   // a0 (hi split)
            afrag[2 + h] = f1;   // a1 (lo split)
        }
    }

    // ---- sweep 64 chunks of 16 codes: 6 MFMA + keyed top-3 per lane ----
    int m1[4], m2[4], m3[4];
#pragma unroll
    for (int r = 0; r < 4; ++r) { m1[r] = m2[r] = m3[r] = 0x7fffffff; }

    const i32x4* bp = reinterpret_cast<const i32x4*>(bprep);
    i32x4 bbuf[2][4];
    float ses[2];
#pragma unroll
    for (int f = 0; f < 4; ++f) bbuf[0][f] = bp[f * 64 + l];
    ses[0] = sesc_g[l & 15];

#pragma unroll 2
    for (int c = 0; c < 64; ++c) {
        const int cur = c & 1, nxt = cur ^ 1;
        if (c < 63) {
#pragma unroll
            for (int f = 0; f < 4; ++f) bbuf[nxt][f] = bp[(c + 1) * 256 + f * 64 + l];
            ses[nxt] = sesc_g[(c + 1) * 16 + (l & 15)];
        }
        bf16x8 b0 = __builtin_bit_cast(bf16x8, bbuf[cur][0]);
        bf16x8 b1 = __builtin_bit_cast(bf16x8, bbuf[cur][1]);
        bf16x8 b2 = __builtin_bit_cast(bf16x8, bbuf[cur][2]);
        bf16x8 b3 = __builtin_bit_cast(bf16x8, bbuf[cur][3]);
        f32x4 accA = {0.f, 0.f, 0.f, 0.f}, accB = {0.f, 0.f, 0.f, 0.f};
        accA = __builtin_amdgcn_mfma_f32_16x16x32_bf16(afrag[0], b0, accA, 0, 0, 0); // a0.b0 klo
        accB = __builtin_amdgcn_mfma_f32_16x16x32_bf16(afrag[1], b1, accB, 0, 0, 0); // a0.b0 khi
        accA = __builtin_amdgcn_mfma_f32_16x16x32_bf16(afrag[0], b2, accA, 0, 0, 0); // a0.b1 klo
        accB = __builtin_amdgcn_mfma_f32_16x16x32_bf16(afrag[1], b3, accB, 0, 0, 0); // a0.b1 khi
        accA = __builtin_amdgcn_mfma_f32_16x16x32_bf16(afrag[2], b0, accA, 0, 0, 0); // a1.b0 klo
        accB = __builtin_amdgcn_mfma_f32_16x16x32_bf16(afrag[3], b1, accB, 0, 0, 0); // a1.b0 khi
        const float sev = ses[cur];
        const int code0 = (c << 4) + (l & 15);
#pragma unroll
        for (int r = 0; r < 4; ++r) {
            float tv = accA[r] + accB[r];
            float uf = fmaf(tv, 2097152.0f, sev);        // (t~)*2^21 (se pre-scaled)
            int u = (((int)uf) << 10) | code0;           // monotone key, code in low 10
            int n1 = min(u, m1[r]);
            int n2 = med3i(u, m1[r], m2[r]);
            int n3 = med3i(max(u, m1[r]), m2[r], m3[r]);
            m1[r] = n1; m2[r] = n2; m3[r] = n3;
        }
    }

    // ---- dump per-lane top-3 keys (C map: row = (l>>4)*4+reg, col = l&15) ----
    {
        const int c0 = l & 15;
#pragma unroll
        for (int r = 0; r < 4; ++r) {
            const int rloc = w * 16 + ((l >> 4) << 2) + r;
            keys_lds[rloc * 49 + c0 * 3 + 0] = m1[r];
            keys_lds[rloc * 49 + c0 * 3 + 1] = m2[r];
            keys_lds[rloc * 49 + c0 * 3 + 2] = m3[r];
        }
    }
    __syncthreads();

    // ---- finalize: exact fp32 re-check of in-margin candidates ----
    if (tid < 64) {
        const int row = tid;
        int mk = 0x7fffffff;
        for (int i = 0; i < 48; ++i) mk = min(mk, keys_lds[row * 49 + i]);
        const int lim = mk + ((169 << 10) + 1023);   // margin 169/2^21 ~ 8e-5 in t units
        const float sx = pairwise64_sq(&x_lds[row * 68]);
        float bestd = 3.4e38f; int besti = KCODES;
        for (int i = 0; i < 48; ++i) {
            int key = keys_lds[row * 49 + i];
            if (key <= lim) {
                int code = key & 1023;
                const float* e = emb + (code << 6);
                float g = 0.0f;
#pragma unroll
                for (int d = 0; d < 64; ++d) g = fmaf(x_lds[row * 68 + d], e[d], g);
                float s_   = sx + se_g[code];    // fl32
                float dist = s_ - 2.0f * g;      // 2g exact; fl32 subtract
                if (dist < bestd || (dist == bestd && code < besti)) { bestd = dist; besti = code; }
            }
        }
        idx_lds[row] = besti;
    }
    __syncthreads();

    // ---- gather winning code rows to LDS ----
    {
        const int r = tid >> 2, seg = tid & 3;
        const float4* src = reinterpret_cast<const float4*>(emb + (idx_lds[r] << 6) + seg * 16);
#pragma unroll
        for (int q = 0; q < 4; ++q) {
            float4 v = src[q];
            int base = r * 68 + seg * 16 + q * 4;
            eq_lds[base + 0] = v.x; eq_lds[base + 1] = v.y;
            eq_lds[base + 2] = v.z; eq_lds[base + 3] = v.w;
        }
    }
    __syncthreads();

    // ---- outputs: q_st (coalesced), inds, loss partial ----
    double lsum = 0.0;
    {
        const float aq = 1.0f / 8388608.0f;   // 2^-23 exactly
        const int row = tid & 63, dbase = (tid >> 6) * 16;
        float* ob = out + ((size_t)b << 18) + hw0 + row;
#pragma unroll
        for (int dd = 0; dd < 16; ++dd) {
            int d = dbase + dd;
            float xv = x_lds[row * 68 + d];
            float qd = eq_lds[row * 68 + d];
            float v  = (xv + aq * qd) + ((1.0f - aq) * qd - xv);
            ob[(size_t)d << 12] = v;
            float diff = qd - xv;
            lsum += (double)diff * (double)diff;
        }
    }
    if (tid < 64) out[OUT_ELEMS + 1 + (size_t)blk * 64 + tid] = (float)idx_lds[tid];

#pragma unroll
    for (int off = 32; off > 0; off >>= 1) lsum += __shfl_down(lsum, off, 64);
    if (l == 0) wsum[w] = lsum;
    __syncthreads();
    if (tid == 0) partials[blk] = (wsum[0] + wsum[1]) + (wsum[2] + wsum[3]);
}

__global__ __launch_bounds__(512) void vq_finish(
    const double* __restrict__ partials, float* __restrict__ out)
{
    __shared__ double lds[8];
    const int t = threadIdx.x;
    double s = partials[t] + partials[t + 512] + partials[t + 1024] + partials[t + 1536];
#pragma unroll
    for (int off = 32; off > 0; off >>= 1) s += __shfl_down(s, off, 64);
    if ((t & 63) == 0) lds[t >> 6] = s;
    __syncthreads();
    if (t == 0) {
        double tot = 0.0;
#pragma unroll
        for (int i = 0; i < 8; ++i) tot += lds[i];
        out[OUT_ELEMS] = (float)(0.75 * tot / (double)OUT_ELEMS);
    }
}

extern "C" void kernel_launch(void* const* d_in, const int* in_sizes, int n_in,
                              void* d_out, int out_size, void* d_ws, size_t ws_size,
                              hipStream_t stream)
{
    const float* lat = (const float*)d_in[0];
    const float* emb = (const float*)d_in[1];
    float* out = (float*)d_out;
    char* ws = (char*)d_ws;

    double* partials        = (double*)(ws + WS_PART);
    float* se               = (float*)(ws + WS_SE);
    float* sesc             = (float*)(ws + WS_SESC);
    unsigned short* bprep   = (unsigned short*)(ws + WS_BPREP);

    prep_se<<<dim3(4),   dim3(256), 0, stream>>>(emb, se, sesc);
    prep_b <<<dim3(64),  dim3(64),  0, stream>>>(emb, bprep);
    vq_main<<<dim3(NBLK), dim3(256), 0, stream>>>(lat, emb, se, sesc, bprep, out, partials);
    vq_finish<<<dim3(1), dim3(512), 0, stream>>>(partials, out);
}

// Round 7
// 97.600 us; speedup vs baseline: 1.2098x; 1.2037x over previous
//
#include <hip/hip_runtime.h>

typedef __attribute__((ext_vector_type(8))) short bf16x8;
typedef __attribute__((ext_vector_type(4))) float f32x4;
typedef __attribute__((ext_vector_type(4))) int   i32x4;

#define NROWS     131072
#define KCODES    1024
#define DDIM      64
#define OUT_ELEMS 8388608
#define NBLK      1024              // 128 rows per block
#define MAGICF    12582912.0f       // 1.5 * 2^23
#define MARGIN    240               // key-quanta (2^-16 in t units); >= 2x worst-case screen err
// d_ws layout
#define WS_PART   0                 // 1024 doubles (8 KB)
#define WS_SE     (8*1024)          // 1024 f32 exact ||e||^2
#define WS_SEM    (12*1024)         // 1024 f32: se*2^16 + MAGICF
#define WS_BPREP  (16*1024)         // 64 chunks * 2 frags * 64 lanes * 16B = 128 KB

// numpy pairwise sum pattern for n=64 (exact fp32; round-2 verified).
__device__ __forceinline__ float pairwise64_sq(const float* __restrict__ v) {
#pragma clang fp contract(off)
    float r[8];
#pragma unroll
    for (int j = 0; j < 8; ++j) r[j] = v[j] * v[j];
#pragma unroll
    for (int i = 8; i < 64; i += 8) {
#pragma unroll
        for (int j = 0; j < 8; ++j) r[j] += v[i + j] * v[i + j];
    }
    return ((r[0] + r[1]) + (r[2] + r[3])) + ((r[4] + r[5]) + (r[6] + r[7]));
}

__device__ __forceinline__ int med3i(int a, int b, int c) {
    int mn = min(a, b), mx = max(a, b);
    return max(mn, min(mx, c));   // v_med3_i32
}

__device__ __forceinline__ unsigned short rne_bf16(float v) {
    unsigned u = __float_as_uint(v);
    return (unsigned short)((u + 0x7fffu + ((u >> 16) & 1u)) >> 16);
}

// One thread per code: exact se, scaled+magic'd sem, single-split bf16 B frags
// (scaled by 2^8, RNE). Frag layout: chunk c=k>>4, frag f=khalf, lane l=g*16+(k&15),
// elems j=0..7 from d = f*32 + g*8 + j.
__global__ __launch_bounds__(256) void vq_prep(
    const float* __restrict__ emb, float* __restrict__ se,
    float* __restrict__ sem, unsigned short* __restrict__ bprep)
{
#pragma clang fp contract(off)
    const int k = blockIdx.x * 256 + threadIdx.x;
    if (k >= KCODES) return;
    const float* e = emb + (k << 6);
    float s = pairwise64_sq(e);
    se[k]  = s;
    sem[k] = (s * 65536.0f) + MAGICF;

    const int c = k >> 4, slot = k & 15;
#pragma unroll
    for (int f = 0; f < 2; ++f) {
#pragma unroll
        for (int g = 0; g < 4; ++g) {
            unsigned short h[8];
#pragma unroll
            for (int j = 0; j < 8; ++j)
                h[j] = rne_bf16(e[f * 32 + g * 8 + j] * 256.0f);
            int4 w;
            w.x = h[0] | (h[1] << 16); w.y = h[2] | (h[3] << 16);
            w.z = h[4] | (h[5] << 16); w.w = h[6] | (h[7] << 16);
            *reinterpret_cast<int4*>(bprep + (((c * 2 + f) * 64 + (g * 16 + slot)) << 3)) = w;
        }
    }
}

__global__ __launch_bounds__(256, 2) void vq_main(
    const float* __restrict__ lat, const float* __restrict__ emb,
    const float* __restrict__ se_g, const float* __restrict__ sem_g,
    const unsigned short* __restrict__ bprep,
    float* __restrict__ out, double* __restrict__ partials)
{
#pragma clang fp contract(off)
    __shared__ float  x_lds[128 * 67];     // 128 rows x 64 d (stride 67: 2-way max)
    __shared__ float  se_lds[KCODES];
    __shared__ float  sem_lds[KCODES];
    __shared__ int    keys_lds[128 * 49];  // 48 keys/row
    __shared__ int    idx_lds[128];
    __shared__ double wsum[4];

    const int tid = threadIdx.x, l = tid & 63, wv = tid >> 6;
    const int blk = blockIdx.x;
    const int n0 = blk * 128, b = n0 >> 12, hw0 = n0 & 4095;

    // ---- stage x (coalesced) + se tables ----
    {
        const int row = tid & 127, dh = (tid >> 7) * 32;
#pragma unroll
        for (int dd = 0; dd < 32; ++dd) {
            int d = dh + dd;
            x_lds[row * 67 + d] = lat[((size_t)b << 18) + ((size_t)d << 12) + hw0 + row];
        }
    }
    for (int i = tid; i < KCODES; i += 256) { se_lds[i] = se_g[i]; sem_lds[i] = sem_g[i]; }
    __syncthreads();

    // ---- A fragments: -2x * 2^8, RNE bf16. Lane map: row=l&15, k=(l>>4)*8+j ----
    bf16x8 afrag[2][2];   // [tile][khalf]
#pragma unroll
    for (int T = 0; T < 2; ++T) {
        const float* xr = x_lds + (wv * 32 + T * 16 + (l & 15)) * 67;
        const int kb = (l >> 4) << 3;
#pragma unroll
        for (int kh = 0; kh < 2; ++kh) {
            bf16x8 f;
#pragma unroll
            for (int j = 0; j < 8; ++j)
                f[j] = (short)rne_bf16(xr[kh * 32 + kb + j] * -512.0f);
            afrag[T][kh] = f;
        }
    }

    // ---- sweep 64 chunks of 16 codes: 4 MFMA + keyed top-3 per (tile,reg) ----
    int m1[2][4], m2[2][4], m3[2][4];
#pragma unroll
    for (int T = 0; T < 2; ++T)
#pragma unroll
        for (int r = 0; r < 4; ++r) { m1[T][r] = m2[T][r] = m3[T][r] = 0x7fffffff; }

    const i32x4* bp = reinterpret_cast<const i32x4*>(bprep);
    i32x4 bbuf[2][2];
    bbuf[0][0] = bp[l];
    bbuf[0][1] = bp[64 + l];

#pragma unroll 2
    for (int c = 0; c < 64; ++c) {
        const int cur = c & 1, nxt = cur ^ 1;
        if (c < 63) {
            bbuf[nxt][0] = bp[(c + 1) * 128 + l];
            bbuf[nxt][1] = bp[(c + 1) * 128 + 64 + l];
        }
        const float sevm = sem_lds[c * 16 + (l & 15)];   // se*2^16 + magic
        bf16x8 b0 = __builtin_bit_cast(bf16x8, bbuf[cur][0]);
        bf16x8 b1 = __builtin_bit_cast(bf16x8, bbuf[cur][1]);
        const unsigned code0 = (unsigned)((c << 4) + (l & 15));
#pragma unroll
        for (int T = 0; T < 2; ++T) {
            f32x4 acc = {0.f, 0.f, 0.f, 0.f};
            acc = __builtin_amdgcn_mfma_f32_16x16x32_bf16(afrag[T][0], b0, acc, 0, 0, 0);
            acc = __builtin_amdgcn_mfma_f32_16x16x32_bf16(afrag[T][1], b1, acc, 0, 0, 0);
#pragma unroll
            for (int r = 0; r < 4; ++r) {
                float uf = acc[r] + sevm;                 // t*2^16 + magic, int-grid
                int key = (int)((__float_as_uint(uf) << 10) | code0);  // monotone
                int n1 = min(key, m1[T][r]);
                int n2 = med3i(key, m1[T][r], m2[T][r]);
                int n3 = med3i(max(key, m1[T][r]), m2[T][r], m3[T][r]);
                m1[T][r] = n1; m2[T][r] = n2; m3[T][r] = n3;
            }
        }
    }

    // ---- dump top-3 keys (C map: row=(l>>4)*4+r, col=l&15) ----
#pragma unroll
    for (int T = 0; T < 2; ++T) {
#pragma unroll
        for (int r = 0; r < 4; ++r) {
            const int rloc = wv * 32 + T * 16 + ((l >> 4) << 2) + r;
            keys_lds[rloc * 49 + (l & 15) * 3 + 0] = m1[T][r];
            keys_lds[rloc * 49 + (l & 15) * 3 + 1] = m2[T][r];
            keys_lds[rloc * 49 + (l & 15) * 3 + 2] = m3[T][r];
        }
    }
    __syncthreads();

    // ---- finalize: exact fp32 re-check of in-margin candidates ----
    if (tid < 128) {
        const int row = tid;
        int mk = 0x7fffffff;
#pragma unroll 4
        for (int i = 0; i < 48; ++i) mk = min(mk, keys_lds[row * 49 + i]);
        const int lim = mk + (MARGIN << 10) + 1023;
        const float* xr = x_lds + row * 67;
        const float sx = pairwise64_sq(xr);
        float bestd = 3.4e38f; int besti = KCODES;
        for (int i = 0; i < 48; ++i) {
            int key = keys_lds[row * 49 + i];
            if (key <= lim) {
                int code = key & 1023;
                const float* e = emb + (code << 6);
                float g = 0.0f;
#pragma unroll
                for (int d = 0; d < 64; ++d) g = fmaf(xr[d], e[d], g);
                float s_   = sx + se_lds[code];   // fl32
                float dist = s_ - 2.0f * g;       // 2g exact; fl32 subtract
                if (dist < bestd || (dist == bestd && code < besti)) { bestd = dist; besti = code; }
            }
        }
        idx_lds[row] = besti;
    }
    __syncthreads();

    // ---- epilogue: q_st (coalesced), inds, loss partial ----
    double lsum = 0.0;
    {
        const float aq = 1.0f / 8388608.0f;   // 2^-23 exactly
        const int row = tid & 127, dh = (tid >> 7) * 32;
        const int code = idx_lds[row];
        float q[32];
        const float4* eq4 = reinterpret_cast<const float4*>(emb + (code << 6) + dh);
#pragma unroll
        for (int qq = 0; qq < 8; ++qq) {
            float4 v = eq4[qq];
            q[qq * 4 + 0] = v.x; q[qq * 4 + 1] = v.y; q[qq * 4 + 2] = v.z; q[qq * 4 + 3] = v.w;
        }
        float* ob = out + ((size_t)b << 18) + hw0 + row;
#pragma unroll
        for (int dd = 0; dd < 32; ++dd) {
            int d = dh + dd;
            float xv = x_lds[row * 67 + d];
            float qd = q[dd];
            float v  = (xv + aq * qd) + ((1.0f - aq) * qd - xv);
            ob[(size_t)d << 12] = v;
            float diff = qd - xv;
            lsum += (double)diff * (double)diff;
        }
    }
    if (tid < 128) out[OUT_ELEMS + 1 + (size_t)n0 + tid] = (float)idx_lds[tid];

#pragma unroll
    for (int off = 32; off > 0; off >>= 1) lsum += __shfl_down(lsum, off, 64);
    if (l == 0) wsum[wv] = lsum;
    __syncthreads();
    if (tid == 0) partials[blk] = (wsum[0] + wsum[1]) + (wsum[2] + wsum[3]);
}

__global__ __launch_bounds__(512) void vq_finish(
    const double* __restrict__ partials, float* __restrict__ out)
{
    __shared__ double lds[8];
    const int t = threadIdx.x;
    double s = partials[t] + partials[t + 512];
#pragma unroll
    for (int off = 32; off > 0; off >>= 1) s += __shfl_down(s, off, 64);
    if ((t & 63) == 0) lds[t >> 6] = s;
    __syncthreads();
    if (t == 0) {
        double tot = 0.0;
#pragma unroll
        for (int i = 0; i < 8; ++i) tot += lds[i];
        out[OUT_ELEMS] = (float)(0.75 * tot / (double)OUT_ELEMS);
    }
}

extern "C" void kernel_launch(void* const* d_in, const int* in_sizes, int n_in,
                              void* d_out, int out_size, void* d_ws, size_t ws_size,
                              hipStream_t stream)
{
    const float* lat = (const float*)d_in[0];
    const float* emb = (const float*)d_in[1];
    float* out = (float*)d_out;
    char* ws = (char*)d_ws;

    double* partials      = (double*)(ws + WS_PART);
    float* se             = (float*)(ws + WS_SE);
    float* sem            = (float*)(ws + WS_SEM);
    unsigned short* bprep = (unsigned short*)(ws + WS_BPREP);

    vq_prep<<<dim3(4),    dim3(256), 0, stream>>>(emb, se, sem, bprep);
    vq_main<<<dim3(NBLK), dim3(256), 0, stream>>>(lat, emb, se, sem, bprep, out, partials);
    vq_finish<<<dim3(1),  dim3(512), 0, stream>>>(partials, out);
}